// Round 2
// baseline (498.084 us; speedup 1.0000x reference)
//
#include <hip/hip_runtime.h>

#define Bn 8
#define Ln 2048
#define Pn 576
#define Vn 32000
#define Dn 2560
#define Tn (Ln - 1 + Pn)          // 2623
#define NROWS (Bn * Tn)           // 20984
#define IGNORE_INDEX (-100)
#define F4_PER_ROW (Dn / 4)       // 640 float4 per row
#define F4_PER_LANE (F4_PER_ROW / 64)  // 10 per lane per row

// Native vector type: __builtin_nontemporal_load/store require a vector of
// scalars, not HIP's struct-wrapped float4.
typedef float f4 __attribute__((ext_vector_type(4)));

// One WAVE per output row, grid-stride. Each wave issues 10 unrolled 16B
// loads (10 KB in flight) then 10 nontemporal 16B stores. The img-vs-token
// decision is wave-uniform (depends only on row), so no divergence; the id
// lookup is wave-uniform -> scalar load. Nontemporal stores keep the 215 MB
// output stream from evicting embed-table rows in L2/L3 (repeat token ids
// ~21% -> L3 hits on the gather).
__global__ __launch_bounds__(256) void splice_kernel(
    const f4* __restrict__ embed_table,     // (V, D/4)
    const f4* __restrict__ image_features,  // (B, P, D/4)
    const int* __restrict__ input_ids,      // (B, L)
    const int* __restrict__ labels,         // (B, L)
    const int* __restrict__ img_pos,        // (B,)
    float* __restrict__ out)                // embeds | labels | mask | pos
{
    const int lane   = threadIdx.x & 63;
    const int wave   = (int)((blockIdx.x * blockDim.x + threadIdx.x) >> 6);
    const int nwaves = (int)((gridDim.x * blockDim.x) >> 6);

    const size_t nBT = (size_t)NROWS;
    float* __restrict__ extras = out + nBT * Dn;   // labels | mask | pos_ids

    for (int row = wave; row < NROWS; row += nwaves) {
        const int b = row / Tn;           // magic-mul, cheap
        const int t = row - b * Tn;
        const int pos = img_pos[b];       // 8 ints, L1/L2-resident

        const bool is_img = (t >= pos) && (t < pos + Pn);

        const f4* __restrict__ src;
        int tok_idx = 0;
        bool img_src = false;
        if (is_img) {
            img_src = true;
            src = image_features + ((size_t)b * Pn + (t - pos)) * F4_PER_ROW;
        } else {
            tok_idx = (t < pos) ? t : (t - Pn + 1);
            tok_idx = min(max(tok_idx, 0), Ln - 1);
            const int id = input_ids[b * Ln + tok_idx];   // wave-uniform
            src = embed_table + (size_t)id * F4_PER_ROW;
        }

        f4* __restrict__ dst = (f4*)(out + (size_t)row * Dn);

        f4 v[F4_PER_LANE];
        if (img_src) {
            // image rows are consumed exactly once -> bypass cache
#pragma unroll
            for (int k = 0; k < F4_PER_LANE; ++k)
                v[k] = __builtin_nontemporal_load(src + lane + (k << 6));
        } else {
            // embed rows may repeat (duplicate token ids) -> keep cacheable
#pragma unroll
            for (int k = 0; k < F4_PER_LANE; ++k)
                v[k] = src[lane + (k << 6)];
        }
#pragma unroll
        for (int k = 0; k < F4_PER_LANE; ++k)
            __builtin_nontemporal_store(v[k], dst + lane + (k << 6));

        if (lane == 0) {
            const float lab = is_img ? (float)IGNORE_INDEX
                                     : (float)labels[b * Ln + tok_idx];
            extras[row]           = lab;        // new_labels (as f32)
            extras[nBT + row]     = 1.0f;       // attention_mask
            extras[2 * nBT + row] = (float)t;   // position_ids
        }
    }
}

extern "C" void kernel_launch(void* const* d_in, const int* in_sizes, int n_in,
                              void* d_out, int out_size, void* d_ws, size_t ws_size,
                              hipStream_t stream) {
    const f4* embed_table    = (const f4*)d_in[0];
    const f4* image_features = (const f4*)d_in[1];
    const int* input_ids     = (const int*)d_in[2];
    const int* labels        = (const int*)d_in[3];
    const int* img_pos       = (const int*)d_in[4];
    float* out = (float*)d_out;

    // 1312 blocks x 256 threads = 5248 waves; ~4 rows per wave, grid-strided.
    dim3 grid(1312);
    dim3 block(256);
    splice_kernel<<<grid, block, 0, stream>>>(embed_table, image_features,
                                              input_ids, labels, img_pos, out);
}

// Round 3
// 483.642 us; speedup vs baseline: 1.0299x; 1.0299x over previous
//
#include <hip/hip_runtime.h>

#define Bn 8
#define Ln 2048
#define Pn 576
#define Vn 32000
#define Dn 2560
#define Tn (Ln - 1 + Pn)          // 2623
#define NROWS (Bn * Tn)           // 20984
#define IGNORE_INDEX (-100)

// Native vector type: __builtin_nontemporal_load/store require a vector of
// scalars, not HIP's struct-wrapped float4.
typedef float f4 __attribute__((ext_vector_type(4)));

// One block per output row (b, t). 640 threads x 16B = 2560 floats = one row.
// This is the measured-best structure (maximal TLP, branch uniform per block).
// Cache policy on top:
//   - output stores are nontemporal (write-once stream, 215 MB) so they don't
//     evict embed-table rows from L2/L3;
//   - image-feature loads are nontemporal (read-exactly-once, 46 MB);
//   - embed-table loads stay cacheable: ~22% of token gathers are repeat ids,
//     which can then hit L3 instead of re-fetching 10 KB rows from HBM.
__global__ __launch_bounds__(640) void splice_kernel(
    const f4* __restrict__ embed_table,     // (V, D/4)
    const f4* __restrict__ image_features,  // (B, P, D/4)
    const int* __restrict__ input_ids,      // (B, L)
    const int* __restrict__ labels,         // (B, L)
    const int* __restrict__ img_pos,        // (B,)
    float* __restrict__ out)                // embeds | labels | mask | pos
{
    const int t = blockIdx.x;      // [0, T)
    const int b = blockIdx.y;      // [0, B)
    const int pos = img_pos[b];

    const bool is_img = (t >= pos) && (t < pos + Pn);

    f4* __restrict__ dst = (f4*)(out + ((size_t)b * Tn + t) * Dn);

    int tok_idx = 0;
    f4 v;
    if (is_img) {
        const int img_idx = t - pos;  // already in [0, P)
        const f4* src = image_features + ((size_t)b * Pn + img_idx) * (Dn / 4);
        v = __builtin_nontemporal_load(src + threadIdx.x);
    } else {
        tok_idx = (t < pos) ? t : (t - Pn + 1);
        tok_idx = min(max(tok_idx, 0), Ln - 1);
        const int id = input_ids[b * Ln + tok_idx];   // block-uniform
        const f4* src = embed_table + (size_t)id * (Dn / 4);
        v = src[threadIdx.x];                          // cacheable (repeats)
    }
    __builtin_nontemporal_store(v, dst + threadIdx.x);

    if (threadIdx.x == 0) {
        const size_t nBT  = (size_t)NROWS;
        const size_t base = nBT * Dn;
        const size_t idx  = (size_t)b * Tn + t;
        const float lab = is_img ? (float)IGNORE_INDEX
                                 : (float)labels[b * Ln + tok_idx];
        out[base + idx]           = lab;        // new_labels (as f32)
        out[base + nBT + idx]     = 1.0f;       // attention_mask
        out[base + 2 * nBT + idx] = (float)t;   // position_ids
    }
}

extern "C" void kernel_launch(void* const* d_in, const int* in_sizes, int n_in,
                              void* d_out, int out_size, void* d_ws, size_t ws_size,
                              hipStream_t stream) {
    const f4* embed_table    = (const f4*)d_in[0];
    const f4* image_features = (const f4*)d_in[1];
    const int* input_ids     = (const int*)d_in[2];
    const int* labels        = (const int*)d_in[3];
    const int* img_pos       = (const int*)d_in[4];
    float* out = (float*)d_out;

    dim3 grid(Tn, Bn);
    dim3 block(640);
    splice_kernel<<<grid, block, 0, stream>>>(embed_table, image_features,
                                              input_ids, labels, img_pos, out);
}